// Round 1
// baseline (264.654 us; speedup 1.0000x reference)
//
#include <hip/hip_runtime.h>

// AttnMap restructure:
//   M[bt][ch][f] = sum_q dec[b, q*16+t, ch] * W[q*8 + (ch>>5)][f]   (ch = g*32+c)
//   out[bt][s][f] = relu( sum_ch enc[bt][s][ch] * M[bt][ch][f] + bias[f] )
// Shapes: b=8, t=16, h*w=1024, C=256, q=16, g=8, F=256.
// Phase 1: 128 blocks, trivial FLOPs. Phase 2: 128 independent 1024x256x256 GEMMs.

#define NQ   16
#define GG   8
#define CCH  256   // input channels (g*c)
#define FF   256   // output features
#define HW   1024  // h*w spatial

__global__ __launch_bounds__(256) void compute_M_kernel(
        const float* __restrict__ dec, const float* __restrict__ W,
        float* __restrict__ M) {
    const int bt = blockIdx.x;            // b*16 + t
    const int b  = bt >> 4, t = bt & 15;
    const int f  = threadIdx.x;           // 0..255
    __shared__ float ldec[NQ][CCH];
    // dec flat: b*65536 + (q*16 + t)*256 + ch
    const float* decbt = dec + (size_t)b * 65536 + (size_t)t * 256;
    for (int i = threadIdx.x; i < NQ * CCH / 4; i += 256) {
        const int q = i >> 6;             // 64 float4 per q-row
        const int seg = i & 63;
        const float4 v = *reinterpret_cast<const float4*>(decbt + q * 4096 + seg * 4);
        *reinterpret_cast<float4*>(&ldec[q][seg * 4]) = v;
    }
    __syncthreads();
    float* Mbt = M + (size_t)bt * (CCH * FF);
    #pragma unroll
    for (int g = 0; g < GG; ++g) {
        float wv[NQ];
        #pragma unroll
        for (int q = 0; q < NQ; ++q) wv[q] = W[(q * GG + g) * FF + f];  // coalesced
        #pragma unroll 4
        for (int cc = 0; cc < 32; ++cc) {
            const int ch = g * 32 + cc;
            float s = 0.f;
            #pragma unroll
            for (int q = 0; q < NQ; ++q) s += ldec[q][ch] * wv[q];      // LDS broadcast
            Mbt[ch * FF + f] = s;                                        // coalesced
        }
    }
}

// Phase 2: per block: one (bt, 128-row, 128-col) output tile.
// 256 threads as 16x16; each thread: 8x8 accumulators.
__global__ __launch_bounds__(256) void gemm_relu_kernel(
        const float* __restrict__ E, const float* __restrict__ M,
        const float* __restrict__ bias, float* __restrict__ O) {
    const int bt   = blockIdx.y;
    const int tile = blockIdx.x;            // 0..15 : 8 row-blocks x 2 col-blocks
    const int rb = (tile >> 1) * 128;
    const int cb = (tile & 1) * 128;
    const float* Ebt = E + (size_t)bt * (HW * CCH);
    const float* Mbt = M + (size_t)bt * (CCH * FF);
    float*       Obt = O + (size_t)bt * (HW * FF);

    __shared__ float Et[32][128];  // [kk][row], transposed E tile
    __shared__ float Mt[32][128];  // [kk][col]

    const int tx = threadIdx.x & 15;   // col group (8 cols each)
    const int ty = threadIdx.x >> 4;   // row group (8 rows each)

    float acc[8][8];
    #pragma unroll
    for (int r = 0; r < 8; ++r)
        #pragma unroll
        for (int c = 0; c < 8; ++c) acc[r][c] = 0.f;

    for (int k0 = 0; k0 < CCH; k0 += 32) {
        // Stage E rows rb..rb+127, k in [k0,k0+32), transposed into Et.
        for (int i = threadIdx.x; i < 1024; i += 256) {
            const int row = i >> 3;        // 0..127
            const int seg = i & 7;         // k offset seg*4
            const float4 v = *reinterpret_cast<const float4*>(
                Ebt + (size_t)(rb + row) * CCH + k0 + seg * 4);
            Et[seg * 4 + 0][row] = v.x;
            Et[seg * 4 + 1][row] = v.y;
            Et[seg * 4 + 2][row] = v.z;
            Et[seg * 4 + 3][row] = v.w;
        }
        // Stage M rows k0..k0+31, cols cb..cb+127 (layout preserved).
        for (int i = threadIdx.x; i < 1024; i += 256) {
            const int kk = i >> 5;         // 0..31
            const int seg = i & 31;        // col seg*4
            const float4 v = *reinterpret_cast<const float4*>(
                Mbt + (size_t)(k0 + kk) * FF + cb + seg * 4);
            *reinterpret_cast<float4*>(&Mt[kk][seg * 4]) = v;
        }
        __syncthreads();

        #pragma unroll 4
        for (int kk = 0; kk < 32; ++kk) {
            float a[8], bb[8];
            *reinterpret_cast<float4*>(a)     = *reinterpret_cast<const float4*>(&Et[kk][ty * 8]);
            *reinterpret_cast<float4*>(a + 4) = *reinterpret_cast<const float4*>(&Et[kk][ty * 8 + 4]);
            *reinterpret_cast<float4*>(bb)     = *reinterpret_cast<const float4*>(&Mt[kk][tx * 8]);
            *reinterpret_cast<float4*>(bb + 4) = *reinterpret_cast<const float4*>(&Mt[kk][tx * 8 + 4]);
            #pragma unroll
            for (int r = 0; r < 8; ++r)
                #pragma unroll
                for (int c = 0; c < 8; ++c)
                    acc[r][c] += a[r] * bb[c];
        }
        __syncthreads();
    }

    // Epilogue: +bias, relu, store.
    float bv[8];
    *reinterpret_cast<float4*>(bv)     = *reinterpret_cast<const float4*>(bias + cb + tx * 8);
    *reinterpret_cast<float4*>(bv + 4) = *reinterpret_cast<const float4*>(bias + cb + tx * 8 + 4);
    #pragma unroll
    for (int r = 0; r < 8; ++r) {
        const int row = rb + ty * 8 + r;
        float* op = Obt + (size_t)row * FF + cb + tx * 8;
        float4 o0, o1;
        o0.x = fmaxf(acc[r][0] + bv[0], 0.f);
        o0.y = fmaxf(acc[r][1] + bv[1], 0.f);
        o0.z = fmaxf(acc[r][2] + bv[2], 0.f);
        o0.w = fmaxf(acc[r][3] + bv[3], 0.f);
        o1.x = fmaxf(acc[r][4] + bv[4], 0.f);
        o1.y = fmaxf(acc[r][5] + bv[5], 0.f);
        o1.z = fmaxf(acc[r][6] + bv[6], 0.f);
        o1.w = fmaxf(acc[r][7] + bv[7], 0.f);
        *reinterpret_cast<float4*>(op)     = o0;
        *reinterpret_cast<float4*>(op + 4) = o1;
    }
}

extern "C" void kernel_launch(void* const* d_in, const int* in_sizes, int n_in,
                              void* d_out, int out_size, void* d_ws, size_t ws_size,
                              hipStream_t stream) {
    const float* dec  = (const float*)d_in[0];   // (8, 256, 256)
    const float* enc  = (const float*)d_in[1];   // (8, 16, 32, 32, 256)
    const float* W    = (const float*)d_in[2];   // (128, 256)
    const float* bias = (const float*)d_in[3];   // (256,)
    float* out = (float*)d_out;                  // (8, 16, 32, 32, 256)
    float* M   = (float*)d_ws;                   // needs 128*256*256*4 = 33.55 MB

    compute_M_kernel<<<dim3(128), dim3(256), 0, stream>>>(dec, W, M);
    gemm_relu_kernel<<<dim3(16, 128), dim3(256), 0, stream>>>(enc, M, bias, out);
}

// Round 2
// 106.015 us; speedup vs baseline: 2.4964x; 2.4964x over previous
//
#include <hip/hip_runtime.h>

// AttnMap restructure (verified round 1 in fp32):
//   Mt[bt][f][ch] = sum_q dec[b, q*16+t, ch] * W[q*8 + (ch>>5)][f]
//   out[bt][s][f] = relu( sum_ch enc[bt][s][ch] * Mt[f][ch] + bias[f] )
// This round: Mt stored bf16 f-major; phase 2 is a bf16 MFMA GEMM
// (128 independent 1024x256x256 GEMMs), fp32 accumulate, fp32 output.

#define CCH  256   // input channels (g*c) == GEMM K
#define FF   256   // output features
#define HW   1024  // h*w spatial rows per bt

typedef __bf16 bf16x8 __attribute__((ext_vector_type(8)));
typedef float  f32x4  __attribute__((ext_vector_type(4)));
typedef unsigned short u16x4 __attribute__((ext_vector_type(4)));
typedef unsigned short u16x8 __attribute__((ext_vector_type(8)));

__device__ __forceinline__ unsigned short f2bf(float f) {
    __bf16 b = (__bf16)f;                       // RNE convert on gfx950
    return __builtin_bit_cast(unsigned short, b);
}

// ---------------- Phase 1: Mt[bt][f][ch] (bf16) ----------------
__global__ __launch_bounds__(256) void compute_Mt_kernel(
        const float* __restrict__ dec, const float* __restrict__ W,
        unsigned short* __restrict__ Mt) {
    const int bt = blockIdx.x;             // b*16 + t
    const int b  = bt >> 4, t = bt & 15;
    __shared__ float  ldec[16][CCH];       // 16 KB: dec rows for this (b,t)
    __shared__ unsigned short stg[256][32];// 16 KB: [f][cc] chunk for transpose-out

    const float* decbt = dec + (size_t)b * 65536 + (size_t)t * 256;
    for (int i = threadIdx.x; i < 16 * CCH / 4; i += 256) {
        const int q = i >> 6, seg = i & 63;
        const float4 v = *reinterpret_cast<const float4*>(decbt + q * 4096 + seg * 4);
        *reinterpret_cast<float4*>(&ldec[q][seg * 4]) = v;
    }
    __syncthreads();

    unsigned short* Mtbt = Mt + (size_t)bt * (FF * CCH);
    const int f = threadIdx.x;
    for (int g = 0; g < 8; ++g) {
        float wv[16];
        #pragma unroll
        for (int q = 0; q < 16; ++q) wv[q] = W[(q * 8 + g) * FF + f];   // coalesced
        #pragma unroll 4
        for (int cc = 0; cc < 32; ++cc) {
            const int ch = g * 32 + cc;
            float s = 0.f;
            #pragma unroll
            for (int q = 0; q < 16; ++q) s += ldec[q][ch] * wv[q];      // LDS broadcast
            stg[f][cc] = f2bf(s);
        }
        __syncthreads();
        // cooperative transposed write-out: rows = f, 32 ch contiguous
        #pragma unroll
        for (int p = 0; p < 8; ++p) {
            const int row = p * 32 + (threadIdx.x >> 3);
            const int seg = threadIdx.x & 7;
            *reinterpret_cast<u16x4*>(Mtbt + (size_t)row * CCH + g * 32 + seg * 4) =
                *reinterpret_cast<const u16x4*>(&stg[row][seg * 4]);
        }
        __syncthreads();
    }
}

// ---------------- Phase 2: out = relu(E @ Mt^T + bias), bf16 MFMA ----------------
// Block: 128 rows x 128 f tile of one bt. 256 threads = 4 waves (2x2).
// Per wave: 64x64 = 4x4 fragments of mfma_f32_16x16x32_bf16, K-steps of 32.
#define LDK 40   // padded row length (bf16 elems): 32 + 8 -> 80B row stride, 16B-aligned
__global__ __launch_bounds__(256) void gemm_mfma_kernel(
        const float* __restrict__ E, const unsigned short* __restrict__ Mt,
        const float* __restrict__ bias, float* __restrict__ O) {
    const int bt   = blockIdx.y;
    const int tile = blockIdx.x;             // 8 row-blocks x 2 col-blocks
    const int rb = (tile >> 1) * 128;
    const int cb = (tile & 1) * 128;
    const float*          Ebt  = E  + (size_t)bt * (HW * CCH);
    const unsigned short* Mtbt = Mt + (size_t)bt * (FF * CCH);
    float*                Obt  = O  + (size_t)bt * (HW * FF);

    __shared__ unsigned short Ea[128][LDK];  // [row][k] bf16, 10 KB
    __shared__ unsigned short Bb[128][LDK];  // [f][k]  bf16, 10 KB

    const int lane = threadIdx.x & 63;
    const int wave = threadIdx.x >> 6;
    const int wm = wave >> 1;                // 0..1 row half
    const int wn = wave & 1;                 // 0..1 col half

    f32x4 acc[4][4];
    #pragma unroll
    for (int i = 0; i < 4; ++i)
        #pragma unroll
        for (int j = 0; j < 4; ++j) acc[i][j] = (f32x4)0.f;

    const int srow = threadIdx.x >> 3, sslot = threadIdx.x & 7;   // E staging
    const int mrow = threadIdx.x >> 2, mslot = threadIdx.x & 3;   // Mt staging
    const int r0 = wm * 64 + (lane & 15);
    const int c0 = wn * 64 + (lane & 15);
    const int kg = (lane >> 4) * 8;

    for (int k0 = 0; k0 < CCH; k0 += 32) {
        // Stage E tile (fp32 -> bf16): 128 rows x 32 k
        #pragma unroll
        for (int p = 0; p < 4; ++p) {
            const int row = p * 32 + srow;
            const float4 v = *reinterpret_cast<const float4*>(
                Ebt + (size_t)(rb + row) * CCH + k0 + sslot * 4);
            u16x4 u = { f2bf(v.x), f2bf(v.y), f2bf(v.z), f2bf(v.w) };
            *reinterpret_cast<u16x4*>(&Ea[row][sslot * 4]) = u;
        }
        // Stage Mt tile (already bf16): 128 f-rows x 32 k
        #pragma unroll
        for (int p = 0; p < 2; ++p) {
            const int row = p * 64 + mrow;
            const u16x8 m = *reinterpret_cast<const u16x8*>(
                Mtbt + (size_t)(cb + row) * CCH + k0 + mslot * 8);
            *reinterpret_cast<u16x8*>(&Bb[row][mslot * 8]) = m;
        }
        __syncthreads();

        bf16x8 Af[4], Bf[4];
        #pragma unroll
        for (int fm = 0; fm < 4; ++fm)
            Af[fm] = *reinterpret_cast<const bf16x8*>(&Ea[r0 + fm * 16][kg]);
        #pragma unroll
        for (int fn = 0; fn < 4; ++fn)
            Bf[fn] = *reinterpret_cast<const bf16x8*>(&Bb[c0 + fn * 16][kg]);
        #pragma unroll
        for (int fm = 0; fm < 4; ++fm)
            #pragma unroll
            for (int fn = 0; fn < 4; ++fn)
                acc[fm][fn] = __builtin_amdgcn_mfma_f32_16x16x32_bf16(
                    Af[fm], Bf[fn], acc[fm][fn], 0, 0, 0);
        __syncthreads();
    }

    // Epilogue. C/D layout (m89-verified): col = lane&15, row = (lane>>4)*4 + reg.
    const int rrow = (lane >> 4) * 4;
    const int ccol = lane & 15;
    float bv[4];
    #pragma unroll
    for (int fn = 0; fn < 4; ++fn) bv[fn] = bias[cb + wn * 64 + fn * 16 + ccol];
    #pragma unroll
    for (int fm = 0; fm < 4; ++fm) {
        #pragma unroll
        for (int r = 0; r < 4; ++r) {
            const int row = rb + wm * 64 + fm * 16 + rrow + r;
            float* op = Obt + (size_t)row * FF;
            #pragma unroll
            for (int fn = 0; fn < 4; ++fn)
                op[cb + wn * 64 + fn * 16 + ccol] =
                    fmaxf(acc[fm][fn][r] + bv[fn], 0.f);
        }
    }
}

extern "C" void kernel_launch(void* const* d_in, const int* in_sizes, int n_in,
                              void* d_out, int out_size, void* d_ws, size_t ws_size,
                              hipStream_t stream) {
    const float* dec  = (const float*)d_in[0];   // (8, 256, 256)
    const float* enc  = (const float*)d_in[1];   // (8, 16, 32, 32, 256)
    const float* W    = (const float*)d_in[2];   // (128, 256)
    const float* bias = (const float*)d_in[3];   // (256,)
    float* out = (float*)d_out;                  // (8, 16, 32, 32, 256) fp32
    unsigned short* Mt = (unsigned short*)d_ws;  // 128*256*256*2 = 16.8 MB bf16

    compute_Mt_kernel<<<dim3(128), dim3(256), 0, stream>>>(dec, W, Mt);
    gemm_mfma_kernel<<<dim3(16, 128), dim3(256), 0, stream>>>(enc, Mt, bias, out);
}

// Round 3
// 99.637 us; speedup vs baseline: 2.6562x; 1.0640x over previous
//
#include <hip/hip_runtime.h>

// AttnMap restructure (verified rounds 1-2):
//   Mt[bt][f][ch] = sum_q dec[b, q*16+t, ch] * W[q*8 + (ch>>5)][f]
//   out[bt][s][f] = relu( sum_ch enc[bt][s][ch] * Mt[f][ch] + bias[f] )
// Phase 2 = 128 independent 1024x256x256 bf16-MFMA GEMMs, fp32 out.
// This round: dbuf LDS + 1-iter prefetch + global_load_lds(16B) for Mt
// (with source-side 16B-slot swizzle) + XCD-chunked block swizzle.

#define CCH  256
#define FF   256
#define HW   1024

typedef __bf16 bf16x8 __attribute__((ext_vector_type(8)));
typedef float  f32x4  __attribute__((ext_vector_type(4)));
typedef unsigned short u16x4 __attribute__((ext_vector_type(4)));
typedef unsigned short u16x8 __attribute__((ext_vector_type(8)));

__device__ __forceinline__ unsigned short f2bf(float f) {
    __bf16 b = (__bf16)f;
    return __builtin_bit_cast(unsigned short, b);
}

__device__ __forceinline__ void gload_lds16(const unsigned short* g, unsigned short* l) {
    __builtin_amdgcn_global_load_lds(
        (const __attribute__((address_space(1))) unsigned int*)g,
        (__attribute__((address_space(3))) unsigned int*)l, 16, 0, 0);
}

// ---------------- Phase 1: Mt[bt][f][ch] (bf16, f-major) ----------------
// grid (4 g-pairs, 128 bt), 256 threads = one per f. Transpose-free:
// thread f computes Mt[f][j*64 .. j*64+64) entirely in registers.
__global__ __launch_bounds__(256) void compute_Mt_kernel(
        const float* __restrict__ dec, const float* __restrict__ W,
        unsigned short* __restrict__ Mt) {
    const int j  = blockIdx.x;            // g-pair: g = 2j, 2j+1
    const int bt = blockIdx.y;
    const int b  = bt >> 4, t = bt & 15;
    const int f  = threadIdx.x;
    __shared__ float ldec[16][64];        // 16 q x 64 ch (this g-pair)

    const float* decbt = dec + (size_t)b * 65536 + (size_t)t * 256 + j * 64;
    {
        const int q = threadIdx.x >> 4, seg = threadIdx.x & 15;
        const float4 v = *reinterpret_cast<const float4*>(decbt + q * 4096 + seg * 4);
        *reinterpret_cast<float4*>(&ldec[q][seg * 4]) = v;
    }
    __syncthreads();

    u16x8 rv[8];
    #pragma unroll
    for (int gi = 0; gi < 2; ++gi) {
        const int g = j * 2 + gi;
        float wv[16];
        #pragma unroll
        for (int q = 0; q < 16; ++q) wv[q] = W[(q * 8 + g) * FF + f];   // coalesced
        #pragma unroll
        for (int cc = 0; cc < 32; ++cc) {
            float s = 0.f;
            #pragma unroll
            for (int q = 0; q < 16; ++q) s += ldec[q][gi * 32 + cc] * wv[q];
            const int idx = gi * 32 + cc;
            rv[idx >> 3][idx & 7] = f2bf(s);
        }
    }
    unsigned short* dst = Mt + (size_t)bt * (FF * CCH) + (size_t)f * CCH + j * 64;
    #pragma unroll
    for (int s = 0; s < 8; ++s)
        *reinterpret_cast<u16x8*>(dst + s * 8) = rv[s];   // 128 B/thread contiguous
}

// ---------------- Phase 2: out = relu(E @ Mt^T + bias), bf16 MFMA ----------------
// 128x128 tile, 256 thr / 4 waves (2x2), BK=32, double-buffered LDS,
// 1-iter prefetch, one __syncthreads per K-step.
__global__ __launch_bounds__(256, 4) void gemm_mfma_kernel(
        const float* __restrict__ E, const unsigned short* __restrict__ Mt,
        const float* __restrict__ bias, float* __restrict__ O) {
    const int id0 = blockIdx.x;                       // 0..2047
    const int id  = ((id0 & 7) << 8) | (id0 >> 3);    // XCD-chunked (2048%8==0)
    const int bt = id >> 4, tile = id & 15;
    const int rb = (tile >> 1) * 128;
    const int cb = (tile & 1) * 128;
    const float*          Ebt  = E  + (size_t)bt * (HW * CCH);
    const unsigned short* Mtbt = Mt + (size_t)bt * (FF * CCH);
    float*                Obt  = O  + (size_t)bt * (HW * FF);

    __shared__ __align__(16) unsigned short Ea[2][128][40];   // pad 40 -> ~2-way
    __shared__ __align__(16) unsigned short Bb[2][128 * 32];  // linear (gload_lds)

    const int tid  = threadIdx.x;
    const int lane = tid & 63, wave = tid >> 6;
    const int wm = wave >> 1, wn = wave & 1;
    const int srow = tid >> 3, sslot = tid & 7;

    f32x4 acc[4][4];
    #pragma unroll
    for (int i = 0; i < 4; ++i)
        #pragma unroll
        for (int jj = 0; jj < 4; ++jj) acc[i][jj] = (f32x4)0.f;

    const int r0 = wm * 64 + (lane & 15);
    const int c0 = wn * 64 + (lane & 15);
    const int kg = (lane >> 4) * 8;
    const int s2 = (lane >> 4) ^ (lane & 3);   // B-read slot swizzle (row&3==lane&3)

    float4 ev[4];
    // ---- prologue: stage k0=0 into buffer 0 ----
    #pragma unroll
    for (int p = 0; p < 4; ++p)
        ev[p] = *reinterpret_cast<const float4*>(
            Ebt + (size_t)(rb + p * 32 + srow) * CCH + sslot * 4);
    #pragma unroll
    for (int pth = 0; pth < 2; ++pth) {
        const int i = pth * 256 + tid;
        const int R = i >> 2, S = i & 3;
        gload_lds16(Mtbt + (size_t)(cb + R) * CCH + ((S ^ (R & 3)) * 8),
                    &Bb[0][i * 8]);
    }
    #pragma unroll
    for (int p = 0; p < 4; ++p) {
        u16x4 u = { f2bf(ev[p].x), f2bf(ev[p].y), f2bf(ev[p].z), f2bf(ev[p].w) };
        *reinterpret_cast<u16x4*>(&Ea[0][p * 32 + srow][sslot * 4]) = u;
    }
    __syncthreads();

    int cur = 0;
    for (int t = 0; t < 8; ++t) {
        const int nb = cur ^ 1;
        const int k1 = (t + 1) * 32;
        if (t < 7) {
            // issue next-tile loads early: E -> regs, Mt -> LDS (async)
            #pragma unroll
            for (int p = 0; p < 4; ++p)
                ev[p] = *reinterpret_cast<const float4*>(
                    Ebt + (size_t)(rb + p * 32 + srow) * CCH + k1 + sslot * 4);
            #pragma unroll
            for (int pth = 0; pth < 2; ++pth) {
                const int i = pth * 256 + tid;
                const int R = i >> 2, S = i & 3;
                gload_lds16(Mtbt + (size_t)(cb + R) * CCH + k1 + ((S ^ (R & 3)) * 8),
                            &Bb[nb][i * 8]);
            }
        }
        // compute current buffer
        bf16x8 Af[4], Bf[4];
        #pragma unroll
        for (int fm = 0; fm < 4; ++fm)
            Af[fm] = *reinterpret_cast<const bf16x8*>(&Ea[cur][r0 + fm * 16][kg]);
        #pragma unroll
        for (int fn = 0; fn < 4; ++fn)
            Bf[fn] = *reinterpret_cast<const bf16x8*>(
                &Bb[cur][(c0 + fn * 16) * 32 + s2 * 8]);
        #pragma unroll
        for (int fm = 0; fm < 4; ++fm)
            #pragma unroll
            for (int fn = 0; fn < 4; ++fn)
                acc[fm][fn] = __builtin_amdgcn_mfma_f32_16x16x32_bf16(
                    Af[fm], Bf[fn], acc[fm][fn], 0, 0, 0);
        if (t < 7) {
            // write prefetched E (compiler inserts vmcnt wait for ev)
            #pragma unroll
            for (int p = 0; p < 4; ++p) {
                u16x4 u = { f2bf(ev[p].x), f2bf(ev[p].y), f2bf(ev[p].z), f2bf(ev[p].w) };
                *reinterpret_cast<u16x4*>(&Ea[nb][p * 32 + srow][sslot * 4]) = u;
            }
        }
        __syncthreads();
        cur = nb;
    }

    // Epilogue. C/D layout: col = lane&15, row = (lane>>4)*4 + reg.
    const int rrow = (lane >> 4) * 4;
    const int ccol = lane & 15;
    float bv[4];
    #pragma unroll
    for (int fn = 0; fn < 4; ++fn) bv[fn] = bias[cb + wn * 64 + fn * 16 + ccol];
    #pragma unroll
    for (int fm = 0; fm < 4; ++fm) {
        #pragma unroll
        for (int r = 0; r < 4; ++r) {
            const int row = rb + wm * 64 + fm * 16 + rrow + r;
            float* op = Obt + (size_t)row * FF;
            #pragma unroll
            for (int fn = 0; fn < 4; ++fn)
                op[cb + wn * 64 + fn * 16 + ccol] =
                    fmaxf(acc[fm][fn][r] + bv[fn], 0.f);
        }
    }
}

extern "C" void kernel_launch(void* const* d_in, const int* in_sizes, int n_in,
                              void* d_out, int out_size, void* d_ws, size_t ws_size,
                              hipStream_t stream) {
    const float* dec  = (const float*)d_in[0];   // (8, 256, 256)
    const float* enc  = (const float*)d_in[1];   // (8, 16, 32, 32, 256)
    const float* W    = (const float*)d_in[2];   // (128, 256)
    const float* bias = (const float*)d_in[3];   // (256,)
    float* out = (float*)d_out;                  // (8, 16, 32, 32, 256) fp32
    unsigned short* Mt = (unsigned short*)d_ws;  // 128*256*256*2 = 16.8 MB bf16

    compute_Mt_kernel<<<dim3(4, 128), dim3(256), 0, stream>>>(dec, W, Mt);
    gemm_mfma_kernel<<<dim3(2048), dim3(256), 0, stream>>>(enc, Mt, bias, out);
}

// Round 4
// 87.109 us; speedup vs baseline: 3.0382x; 1.1438x over previous
//
#include <hip/hip_runtime.h>

// AttnMap restructure (verified rounds 1-3):
//   Mt[bt][f][ch] = sum_q dec[b, q*16+t, ch] * W[q*8 + (ch>>5)][f]
//   out[bt][s][f] = relu( sum_ch enc[bt][s][ch] * Mt[f][ch] + bias[f] )
// Round 4: barrier-free streaming GEMM. One wave per (bt, row-quarter,
// f-quarter); whole B-slice (64f x 256k) held in 128 VGPRs; A streamed
// from global with in-register fp32->bf16 cvt. No LDS, no __syncthreads.

#define CCH  256
#define FF   256
#define HW   1024

typedef __bf16 bf16x8 __attribute__((ext_vector_type(8)));
typedef float  f32x4  __attribute__((ext_vector_type(4)));
typedef unsigned short u16x8 __attribute__((ext_vector_type(8)));

__device__ __forceinline__ unsigned short f2bf(float f) {
    __bf16 b = (__bf16)f;
    return __builtin_bit_cast(unsigned short, b);
}

// ---------------- Phase 1: Mt[bt][f][ch] (bf16, f-major) ----------------
// grid (4 g-pairs, 128 bt), 256 threads = one per f; transpose-free.
__global__ __launch_bounds__(256) void compute_Mt_kernel(
        const float* __restrict__ dec, const float* __restrict__ W,
        unsigned short* __restrict__ Mt) {
    const int j  = blockIdx.x;            // g-pair: g = 2j, 2j+1
    const int bt = blockIdx.y;
    const int b  = bt >> 4, t = bt & 15;
    const int f  = threadIdx.x;
    __shared__ float ldec[16][64];        // 16 q x 64 ch (this g-pair)

    const float* decbt = dec + (size_t)b * 65536 + (size_t)t * 256 + j * 64;
    {
        const int q = threadIdx.x >> 4, seg = threadIdx.x & 15;
        const float4 v = *reinterpret_cast<const float4*>(decbt + q * 4096 + seg * 4);
        *reinterpret_cast<float4*>(&ldec[q][seg * 4]) = v;
    }
    __syncthreads();

    u16x8 rv[8];
    #pragma unroll
    for (int gi = 0; gi < 2; ++gi) {
        const int g = j * 2 + gi;
        float wv[16];
        #pragma unroll
        for (int q = 0; q < 16; ++q) wv[q] = W[(q * 8 + g) * FF + f];   // coalesced
        #pragma unroll
        for (int cc = 0; cc < 32; ++cc) {
            float s = 0.f;
            #pragma unroll
            for (int q = 0; q < 16; ++q) s += ldec[q][gi * 32 + cc] * wv[q];
            const int idx = gi * 32 + cc;
            rv[idx >> 3][idx & 7] = f2bf(s);
        }
    }
    unsigned short* dst = Mt + (size_t)bt * (FF * CCH) + (size_t)f * CCH + j * 64;
    #pragma unroll
    for (int s = 0; s < 8; ++s)
        *reinterpret_cast<u16x8*>(dst + s * 8) = rv[s];   // 128 B/thread contiguous
}

// ---------------- Phase 2: barrier-free streaming MFMA GEMM ----------------
// 2048 blocks x 64 threads (1 wave). id -> (bt, rq, fq):
//   wave computes out[bt][rq*256 .. +256)[fq*64 .. +64).
// B-slice in regs: Bf[fn][kk] = Mt[fq*64+fn*16+(lane&15)][kk*32+(lane>>4)*8 ..+8)
// A streamed per 16-row chunk, same lane->(row,k) mapping (k-perm cancels).
// C/D layout (m89-verified): col = lane&15, row = (lane>>4)*4 + reg.
__global__ __launch_bounds__(64, 2) void gemm_stream_kernel(
        const float* __restrict__ E, const unsigned short* __restrict__ Mt,
        const float* __restrict__ bias, float* __restrict__ O) {
    const int id0 = blockIdx.x;                       // 0..2047
    const int id  = ((id0 & 7) << 8) | (id0 >> 3);    // XCD-chunked bijection
    const int bt = id >> 4;
    const int rq = (id >> 2) & 3;                     // row quarter (256 rows)
    const int fq = id & 3;                            // f quarter (64 f)
    const int lane = threadIdx.x;                     // 0..63
    const int lr = lane & 15;                         // row / f within 16
    const int lg = lane >> 4;                         // k-group 0..3

    const float*          Ebt = E  + (size_t)bt * (HW * CCH);
    const unsigned short* Mtb = Mt + (size_t)bt * (FF * CCH) + (size_t)(fq * 64) * CCH;
    float*                Obt = O  + (size_t)bt * (HW * FF);

    // ---- load whole B-slice into registers (once) ----
    bf16x8 Bf[4][8];
    #pragma unroll
    for (int fn = 0; fn < 4; ++fn) {
        const unsigned short* bp = Mtb + (size_t)(fn * 16 + lr) * CCH + lg * 8;
        #pragma unroll
        for (int kk = 0; kk < 8; ++kk)
            Bf[fn][kk] = *reinterpret_cast<const bf16x8*>(bp + kk * 32);
    }
    float bv[4];
    #pragma unroll
    for (int fn = 0; fn < 4; ++fn) bv[fn] = bias[fq * 64 + fn * 16 + lr];

    // ---- stream 16 chunks of 16 rows ----
    for (int c = 0; c < 16; ++c) {
        const int r0 = rq * 256 + c * 16;
        const float* ap = Ebt + (size_t)(r0 + lr) * CCH + lg * 8;
        f32x4 Av[16];
        #pragma unroll
        for (int kk = 0; kk < 8; ++kk) {      // issue all 16 loads up front
            Av[2 * kk]     = *reinterpret_cast<const f32x4*>(ap + kk * 32);
            Av[2 * kk + 1] = *reinterpret_cast<const f32x4*>(ap + kk * 32 + 4);
        }
        f32x4 acc[4];
        #pragma unroll
        for (int fn = 0; fn < 4; ++fn) acc[fn] = (f32x4)0.f;
        #pragma unroll
        for (int kk = 0; kk < 8; ++kk) {
            bf16x8 a8;
            #pragma unroll
            for (int jj = 0; jj < 4; ++jj) {
                a8[jj]     = (__bf16)Av[2 * kk][jj];
                a8[4 + jj] = (__bf16)Av[2 * kk + 1][jj];
            }
            #pragma unroll
            for (int fn = 0; fn < 4; ++fn)
                acc[fn] = __builtin_amdgcn_mfma_f32_16x16x32_bf16(
                    a8, Bf[fn][kk], acc[fn], 0, 0, 0);
        }
        // stores: 4B dwords, 16-lane (64B) contiguous; fn loop covers 64f span
        #pragma unroll
        for (int fn = 0; fn < 4; ++fn) {
            #pragma unroll
            for (int r = 0; r < 4; ++r) {
                const int row = r0 + lg * 4 + r;
                const float v = fmaxf(acc[fn][r] + bv[fn], 0.f);
                __builtin_nontemporal_store(
                    v, Obt + (size_t)row * FF + fq * 64 + fn * 16 + lr);
            }
        }
    }
}

extern "C" void kernel_launch(void* const* d_in, const int* in_sizes, int n_in,
                              void* d_out, int out_size, void* d_ws, size_t ws_size,
                              hipStream_t stream) {
    const float* dec  = (const float*)d_in[0];   // (8, 256, 256)
    const float* enc  = (const float*)d_in[1];   // (8, 16, 32, 32, 256)
    const float* W    = (const float*)d_in[2];   // (128, 256)
    const float* bias = (const float*)d_in[3];   // (256,)
    float* out = (float*)d_out;                  // (8, 16, 32, 32, 256) fp32
    unsigned short* Mt = (unsigned short*)d_ws;  // 128*256*256*2 = 16.8 MB bf16

    compute_Mt_kernel<<<dim3(4, 128), dim3(256), 0, stream>>>(dec, W, Mt);
    gemm_stream_kernel<<<dim3(2048), dim3(64), 0, stream>>>(enc, Mt, bias, out);
}